// Round 1
// baseline (487.326 us; speedup 1.0000x reference)
//
#include <hip/hip_runtime.h>
#include <math.h>

#define Bb 32
#define Nn 1024
#define Mm 64
#define Rr 4
#define Hh 512
#define NINq 256
#define Pp 471
#define EPSN 1e-8f

__device__ __forceinline__ float sigm(float x){ return 1.0f/(1.0f+expf(-x)); }

// ---------------- K1: LSTM gates GEMM ----------------
// grid 32 (col-blocks of 64), block 256 = 64 cols x 4 bgroups (8 b each)
__global__ __launch_bounds__(256) void k_gates(
    const float* __restrict__ X, const float* __restrict__ prev_read,
    const float* __restrict__ h0, const float* __restrict__ Wx,
    const float* __restrict__ Wh, const float* __restrict__ bias,
    float* __restrict__ gates)
{
  __shared__ float lin[32][64];
  const int tid = threadIdx.x;
  const int col = blockIdx.x*64 + (tid & 63);
  const int bg  = tid >> 6;
  float acc[8];
#pragma unroll
  for (int i=0;i<8;i++) acc[i]=0.f;
  // inp = concat(X[256], prev_read[256]) @ Wx
  for (int kc=0; kc<8; ++kc) {
    int k0 = kc*64;
#pragma unroll
    for (int q=0;q<8;q++){
      int idx = tid + 256*q;
      int bb = idx >> 6, kk = idx & 63;
      int k = k0 + kk;
      float v = (k < NINq) ? X[bb*NINq + k] : prev_read[bb*(Rr*Mm) + (k-NINq)];
      lin[bb][kk] = v;
    }
    __syncthreads();
    for (int kk=0; kk<64; ++kk){
      float wv = Wx[(k0+kk)*2048 + col];
#pragma unroll
      for (int bb=0; bb<8; ++bb) acc[bb] += wv * lin[bg*8+bb][kk];
    }
    __syncthreads();
  }
  // + h0 @ Wh
  for (int kc=0; kc<8; ++kc) {
    int k0 = kc*64;
#pragma unroll
    for (int q=0;q<8;q++){
      int idx = tid + 256*q;
      int bb = idx >> 6, kk = idx & 63;
      lin[bb][kk] = h0[bb*Hh + k0 + kk];
    }
    __syncthreads();
    for (int kk=0; kk<64; ++kk){
      float wv = Wh[(k0+kk)*2048 + col];
#pragma unroll
      for (int bb=0; bb<8; ++bb) acc[bb] += wv * lin[bg*8+bb][kk];
    }
    __syncthreads();
  }
  float bv = bias[col];
#pragma unroll
  for (int bb=0; bb<8; ++bb) gates[(bg*8+bb)*2048 + col] = acc[bb] + bv;
}

// ---------------- K2: LSTM epilogue -> h ----------------
__global__ void k_lstm_ep(const float* __restrict__ gates, const float* __restrict__ c0,
                          float* __restrict__ h)
{
  int idx = blockIdx.x*blockDim.x + threadIdx.x;
  if (idx >= Bb*Hh) return;
  int b = idx >> 9, j = idx & 511;
  const float* g = gates + b*2048;
  float gi = g[j], gf = g[j+512], gg = g[j+1024], go = g[j+1536];
  float c = sigm(gf)*c0[idx] + sigm(gi)*tanhf(gg);
  h[idx] = sigm(go)*tanhf(c);
}

// ---------------- K3: param head GEMM + LayerNorm ----------------
// grid B, block 512 (thread = output col, cols >= 471 idle)
__global__ __launch_bounds__(512) void k_pvec(
    const float* __restrict__ h, const float* __restrict__ emb,
    const float* __restrict__ Wp, const float* __restrict__ bp,
    const float* __restrict__ ln_g, const float* __restrict__ ln_b,
    float* __restrict__ pvec)
{
  __shared__ float x[1024];
  __shared__ float red[8];
  int b = blockIdx.x, tid = threadIdx.x;
  x[tid]       = h[b*Hh + tid];
  x[tid + 512] = emb[b*Hh + tid];
  __syncthreads();
  float acc = 0.f;
  if (tid < Pp) {
    acc = bp[tid];
    for (int k=0;k<1024;k++) acc += x[k]*Wp[k*Pp + tid];
  }
  // mean
  float v = (tid < Pp) ? acc : 0.f;
  float s = v;
  for (int o=32;o;o>>=1) s += __shfl_xor(s,o,64);
  if ((tid&63)==0) red[tid>>6] = s;
  __syncthreads();
  if (tid < 8){ float xx = red[tid]; for (int o=4;o;o>>=1) xx += __shfl_xor(xx,o,64); if (!tid) red[0]=xx; }
  __syncthreads();
  float mu = red[0] / (float)Pp;
  __syncthreads();
  // var
  float d = (tid < Pp) ? (acc - mu) : 0.f;
  float s2 = d*d;
  for (int o=32;o;o>>=1) s2 += __shfl_xor(s2,o,64);
  if ((tid&63)==0) red[tid>>6] = s2;
  __syncthreads();
  if (tid < 8){ float xx = red[tid]; for (int o=4;o;o>>=1) xx += __shfl_xor(xx,o,64); if (!tid) red[0]=xx; }
  __syncthreads();
  float var = red[0] / (float)Pp;
  if (tid < Pp) {
    float y = d / sqrtf(var + 1e-5f) * ln_g[tid] + ln_b[tid];
    pvec[b*512 + tid] = y;
  }
}

// ---------------- K4: usage + allocation (bitonic argsort) ----------------
__global__ __launch_bounds__(1024) void k_alloc(
    const float* __restrict__ pvec, const float* __restrict__ rwp,
    const float* __restrict__ wwp, const float* __restrict__ up,
    float* __restrict__ alloc)
{
  __shared__ unsigned long long sk[1024];
  __shared__ float sf[1024];
  __shared__ float fg[4];
  int b = blockIdx.x, tid = threadIdx.x;
  if (tid < 4) fg[tid] = sigm(pvec[b*512 + 128 + tid]);
  __syncthreads();
  float psi = 1.f;
#pragma unroll
  for (int r=0;r<4;r++) psi *= 1.f - fg[r]*rwp[b*(Rr*Nn) + r*Nn + tid];
  float u = up[b*Nn+tid], w = wwp[b*Nn+tid];
  float usage = (u + w - u*w)*psi;               // >= 0 always
  sk[tid] = ((unsigned long long)__float_as_uint(usage) << 32) | (unsigned)tid;
  __syncthreads();
  for (int k=2; k<=1024; k<<=1)
    for (int j=k>>1; j>0; j>>=1) {
      int ixj = tid ^ j;
      if (ixj > tid) {
        unsigned long long a = sk[tid], c = sk[ixj];
        bool asc = ((tid & k) == 0);
        if ((a > c) == asc) { sk[tid]=c; sk[ixj]=a; }
      }
      __syncthreads();
    }
  unsigned long long key = sk[tid];
  float us = __uint_as_float((unsigned)(key >> 32));
  int order = (int)(key & 1023u);
  sf[tid] = us;
  for (int dd=1; dd<1024; dd<<=1) {
    __syncthreads();
    float p = (tid >= dd) ? sf[tid-dd] : 1.f;
    float cur = sf[tid];
    __syncthreads();
    sf[tid] = cur * p;
  }
  __syncthreads();
  alloc[b*Nn + order] = (1.f - us) * sf[tid];
}

// ---------------- K5: write content -> ww, plus Sp/Sw scalars ----------------
__global__ __launch_bounds__(1024) void k_ww(
    const float* __restrict__ pvec, const float* __restrict__ mem,
    const float* __restrict__ alloc, const float* __restrict__ prec,
    const float* __restrict__ rwp, float* __restrict__ wwb, float* __restrict__ spsw)
{
  __shared__ float kdir[64];
  __shared__ float sim[1024];
  __shared__ float red[16];
  __shared__ float red8[16][8];
  __shared__ float scal[4];
  int b = blockIdx.x, tid = threadIdx.x;
  int wv = tid >> 6, lane = tid & 63;
  const float* pv = pvec + b*512;
  if (tid < 64) kdir[tid] = pv[146 + tid];
  if (wv == 0) {
    float v = kdir[lane];
    float s = v*v;
    for (int o=32;o;o>>=1) s += __shfl_xor(s,o,64);
    kdir[lane] = v / (sqrtf(s) + EPSN);
  }
  if (tid == 0) {
    scal[1] = 1.f + log1pf(expf(pv[210]));  // write strength
    scal[2] = sigm(pv[132]);                // alloc gate
    scal[3] = sigm(pv[133]);                // write gate
  }
  __syncthreads();
  float beta = scal[1], ag = scal[2], wg = scal[3];
  for (int t=0; t<64; ++t) {
    int n = wv*64 + t;
    float v = mem[(b*Nn + n)*Mm + lane];
    float d = v * kdir[lane];
    float s2 = v*v;
    for (int o=32;o;o>>=1){ d += __shfl_xor(d,o,64); s2 += __shfl_xor(s2,o,64); }
    if (lane == 0) sim[n] = beta * (d / (sqrtf(s2) + EPSN));
  }
  __syncthreads();
  // softmax over N
  float v = sim[tid];
  float m_ = v;
  for (int o=32;o;o>>=1) m_ = fmaxf(m_, __shfl_xor(m_,o,64));
  if (lane==0) red[wv] = m_;
  __syncthreads();
  if (tid < 16){ float x = red[tid]; for (int o=8;o;o>>=1) x = fmaxf(x,__shfl_xor(x,o,64)); if (!tid) red[0]=x; }
  __syncthreads();
  float gmax = red[0];
  __syncthreads();
  float e = expf(v - gmax);
  float ss = e;
  for (int o=32;o;o>>=1) ss += __shfl_xor(ss,o,64);
  if (lane==0) red[wv] = ss;
  __syncthreads();
  if (tid < 16){ float x = red[tid]; for (int o=8;o;o>>=1) x += __shfl_xor(x,o,64); if (!tid) red[0]=x; }
  __syncthreads();
  float wcn = e / red[0];
  __syncthreads();
  float an = alloc[b*Nn + tid];
  float wwn = wg * (ag*an + (1.f-ag)*wcn);
  wwb[b*Nn + tid] = wwn;
  // Sp[r] = sum p*a_r ; Sw[r] = sum ww*a_r
  float p = prec[b*Nn + tid];
#pragma unroll
  for (int r=0;r<4;r++){
    float a = rwp[b*(Rr*Nn) + r*Nn + tid];
    float x1 = p*a, x2 = wwn*a;
    for (int o=32;o;o>>=1){ x1 += __shfl_xor(x1,o,64); x2 += __shfl_xor(x2,o,64); }
    if (lane==0){ red8[wv][r] = x1; red8[wv][4+r] = x2; }
  }
  __syncthreads();
  if (tid < 8) {
    float s = 0.f;
    for (int w2=0; w2<16; ++w2) s += red8[w2][tid];
    spsw[b*8 + tid] = s;   // [0..3]=Sp, [4..7]=Sw
  }
}

// ---------------- K6: memory update + inverse norms ----------------
__global__ __launch_bounds__(256) void k_memupd(
    const float* __restrict__ pvec, const float* __restrict__ mem,
    const float* __restrict__ wwb, float* __restrict__ memn, float* __restrict__ inorm)
{
  __shared__ float ev[64], wvv[64];
  int b = blockIdx.y, tid = threadIdx.x;
  int wv = tid>>6, lane = tid&63;
  const float* pv = pvec + b*512;
  if (tid < 64) { wvv[tid] = pv[tid]; ev[tid] = sigm(pv[64+tid]); }
  __syncthreads();
  for (int t=0;t<16;++t){
    int n = blockIdx.x*64 + wv*16 + t;
    float wwn = wwb[b*Nn + n];
    float v = mem[(b*Nn+n)*Mm + lane];
    float nv = v*(1.f - wwn*ev[lane]) + wwn*wvv[lane];
    memn[(b*Nn+n)*Mm + lane] = nv;
    float s = nv*nv;
    for (int o=32;o;o>>=1) s += __shfl_xor(s,o,64);
    if (lane==0) inorm[b*Nn+n] = 1.f/(sqrtf(s)+EPSN);
  }
}

__global__ void k_zero(float* __restrict__ p, int n){
  int i = blockIdx.x*blockDim.x + threadIdx.x;
  if (i < n) p[i] = 0.f;
}

// ---------------- K8: column dots of links (for bwd) ----------------
// grid (16 j-chunks, B), block 1024 (thread = column i)
__global__ __launch_bounds__(1024) void k_bwdcols(
    const float* __restrict__ links, const float* __restrict__ rwp,
    const float* __restrict__ wwb, float* __restrict__ T1, float* __restrict__ T2)
{
  __shared__ float a4[4][64], wa4[4][64];
  int b = blockIdx.y, j0 = blockIdx.x*64, tid = threadIdx.x;
  if (tid < 256) {
    int r = tid>>6, jj = tid&63;
    float a = rwp[b*(Rr*Nn) + r*Nn + j0+jj];
    a4[r][jj] = a;
    wa4[r][jj] = a * wwb[b*Nn + j0+jj];
  }
  __syncthreads();
  float t1[4]={0,0,0,0}, t2[4]={0,0,0,0};
  const float* Lb = links + (size_t)b*Nn*Nn;
  for (int jj=0; jj<64; ++jj) {
    float v = Lb[(size_t)(j0+jj)*Nn + tid];
#pragma unroll
    for (int r=0;r<4;r++){ t1[r] += v*a4[r][jj]; t2[r] += v*wa4[r][jj]; }
  }
#pragma unroll
  for (int r=0;r<4;r++){
    atomicAdd(&T1[(b*4+r)*Nn + tid], t1[r]);
    atomicAdd(&T2[(b*4+r)*Nn + tid], t2[r]);
  }
}

// ---------------- K9: row dots of links (for fwd) ----------------
// grid (16 i-chunks, B), block 256 (4 waves, wave = one row at a time)
__global__ __launch_bounds__(256) void k_fwdrows(
    const float* __restrict__ links, const float* __restrict__ rwp,
    const float* __restrict__ wwb, float* __restrict__ S1, float* __restrict__ S2)
{
  __shared__ float a4[4096], wa4[4096];
  int b = blockIdx.y, i0 = blockIdx.x*64, tid = threadIdx.x;
  int wv = tid>>6, lane = tid&63;
  for (int q=0;q<16;q++){
    int idx = tid + 256*q;
    float a = rwp[b*(Rr*Nn) + idx];
    a4[idx] = a;
    wa4[idx] = a * wwb[b*Nn + (idx & 1023)];
  }
  __syncthreads();
  const float* Lb = links + (size_t)b*Nn*Nn;
  for (int t=0;t<16;++t){
    int i = i0 + wv*16 + t;
    float s1[4]={0,0,0,0}, s2[4]={0,0,0,0};
    const float* Lr = Lb + (size_t)i*Nn;
    for (int it=0; it<16; ++it){
      int j = lane + it*64;
      float v = Lr[j];
#pragma unroll
      for (int r=0;r<4;r++){ s1[r] += v*a4[r*Nn+j]; s2[r] += v*wa4[r*Nn+j]; }
    }
#pragma unroll
    for (int r=0;r<4;r++){
      float x1=s1[r], x2=s2[r];
      for (int o=32;o;o>>=1){ x1 += __shfl_xor(x1,o,64); x2 += __shfl_xor(x2,o,64); }
      if (lane==0){ S1[(b*4+r)*Nn + i] = x1; S2[(b*4+r)*Nn + i] = x2; }
    }
  }
}

// ---------------- K10: read content + rw combine + reads GEMV ----------------
__global__ __launch_bounds__(1024) void k_read(
    const float* __restrict__ pvec, const float* __restrict__ memn,
    const float* __restrict__ inorm, const float* __restrict__ links,
    const float* __restrict__ rwp, const float* __restrict__ prec,
    const float* __restrict__ wwb, const float* __restrict__ T1,
    const float* __restrict__ T2, const float* __restrict__ S1,
    const float* __restrict__ S2, const float* __restrict__ spsw,
    float* __restrict__ readsb)
{
  __shared__ float kdir[4][64];
  __shared__ float sim[4][1024];
  __shared__ float wws[1024];
  __shared__ float red[16];
  __shared__ float rm[4][3];
  __shared__ float beta[4];
  __shared__ float rp[16][64];
  int b = blockIdx.x, tid = threadIdx.x;
  int wv = tid>>6, lane = tid&63;
  const float* pv = pvec + b*512;
  if (wv < 4) {
    float v = pv[211 + wv*64 + lane];
    float s = v*v;
    for (int o=32;o;o>>=1) s += __shfl_xor(s,o,64);
    kdir[wv][lane] = v/(sqrtf(s)+EPSN);
    if (lane==0) beta[wv] = 1.f + log1pf(expf(pv[467+wv]));
  }
  if (tid < 4) {
    float x0 = pv[134 + tid*3], x1 = pv[134+tid*3+1], x2 = pv[134+tid*3+2];
    float mx = fmaxf(x0, fmaxf(x1,x2));
    float e0 = expf(x0-mx), e1=expf(x1-mx), e2=expf(x2-mx);
    float s = e0+e1+e2;
    rm[tid][0]=e0/s; rm[tid][1]=e1/s; rm[tid][2]=e2/s;
  }
  wws[tid] = wwb[b*Nn + tid];
  __syncthreads();
  // cosine sims vs updated memory
  for (int t=0;t<64;++t){
    int n = wv*64 + t;
    float v = memn[(b*Nn+n)*Mm + lane];
    float d0=v*kdir[0][lane], d1=v*kdir[1][lane], d2=v*kdir[2][lane], d3=v*kdir[3][lane];
    for (int o=32;o;o>>=1){ d0+=__shfl_xor(d0,o,64); d1+=__shfl_xor(d1,o,64); d2+=__shfl_xor(d2,o,64); d3+=__shfl_xor(d3,o,64); }
    if (lane==0){
      float inv = inorm[b*Nn+n];
      sim[0][n]=beta[0]*d0*inv; sim[1][n]=beta[1]*d1*inv;
      sim[2][n]=beta[2]*d2*inv; sim[3][n]=beta[3]*d3*inv;
    }
  }
  __syncthreads();
  float Lii = links[(size_t)b*Nn*Nn + (size_t)tid*Nn + tid];
  float w_n = wws[tid];
  float p_n = prec[b*Nn + tid];
  for (int r=0;r<4;r++){
    float v = sim[r][tid];
    float m_ = v;
    for (int o=32;o;o>>=1) m_ = fmaxf(m_, __shfl_xor(m_,o,64));
    if (lane==0) red[wv]=m_;
    __syncthreads();
    if (tid<16){ float x=red[tid]; for(int o=8;o;o>>=1) x=fmaxf(x,__shfl_xor(x,o,64)); if(!tid) red[0]=x; }
    __syncthreads();
    float gmax = red[0];
    __syncthreads();
    float e = expf(v-gmax);
    float s = e;
    for (int o=32;o;o>>=1) s += __shfl_xor(s,o,64);
    if (lane==0) red[wv]=s;
    __syncthreads();
    if (tid<16){ float x=red[tid]; for(int o=8;o;o>>=1) x+=__shfl_xor(x,o,64); if(!tid) red[0]=x; }
    __syncthreads();
    float rc = e/red[0];
    __syncthreads();
    float a = rwp[b*(Rr*Nn)+r*Nn+tid];
    float s1v = S1[(b*4+r)*Nn+tid], s2v = S2[(b*4+r)*Nn+tid];
    float t1v = T1[(b*4+r)*Nn+tid], t2v = T2[(b*4+r)*Nn+tid];
    float Spr = spsw[b*8+r], Swr = spsw[b*8+4+r];
    float fwd = (1.f-w_n)*(s1v - Lii*a) - (s2v - Lii*w_n*a) + w_n*(Spr - p_n*a);
    float bwd = (1.f-w_n)*(t1v - Lii*a) - (t2v - w_n*Lii*a) + p_n*(Swr - w_n*a);
    sim[r][tid] = rm[r][1]*rc + rm[r][0]*bwd + rm[r][2]*fwd;   // rw
  }
  __syncthreads();
  // reads = rw @ mem_new
  int r = wv >> 2, ch = wv & 3;
  float acc = 0.f;
  for (int t=0;t<256;++t){
    int n = ch*256 + t;
    acc += sim[r][n] * memn[(b*Nn+n)*Mm + lane];
  }
  rp[wv][lane] = acc;
  __syncthreads();
  if (tid < 256) {
    int rr = tid>>6, m = tid&63;
    float s = rp[rr*4+0][m]+rp[rr*4+1][m]+rp[rr*4+2][m]+rp[rr*4+3][m];
    readsb[b*(Rr*Mm) + rr*64 + m] = s;
  }
}

// ---------------- K11: output GEMM ----------------
__global__ __launch_bounds__(256) void k_out(
    const float* __restrict__ h, const float* __restrict__ emb,
    const float* __restrict__ readsb, const float* __restrict__ Wo,
    const float* __restrict__ bo, float* __restrict__ out)
{
  __shared__ float x[1280];
  int b = blockIdx.x, tid = threadIdx.x;
#pragma unroll
  for (int q=0;q<5;q++){
    int idx = tid + 256*q;
    float v;
    if (idx < 512) v = h[b*512+idx];
    else if (idx < 1024) v = emb[b*512 + idx-512];
    else v = readsb[b*256 + idx-1024];
    x[idx] = v;
  }
  __syncthreads();
  float acc = bo[tid];
  for (int k=0;k<1280;k++) acc += x[k]*Wo[k*256 + tid];
  out[b*256 + tid] = acc;
}

extern "C" void kernel_launch(void* const* d_in, const int* in_sizes, int n_in,
                              void* d_out, int out_size, void* d_ws, size_t ws_size,
                              hipStream_t stream)
{
  (void)in_sizes; (void)n_in; (void)out_size; (void)ws_size;
  const float* X    = (const float*)d_in[0];
  const float* emb  = (const float*)d_in[1];
  const float* mem  = (const float*)d_in[2];
  const float* prvr = (const float*)d_in[3];
  const float* h0   = (const float*)d_in[4];
  const float* c0   = (const float*)d_in[5];
  const float* rwp  = (const float*)d_in[6];
  const float* wwp  = (const float*)d_in[7];
  const float* up   = (const float*)d_in[8];
  const float* prec = (const float*)d_in[9];
  const float* links= (const float*)d_in[10];
  const float* Wx   = (const float*)d_in[11];
  const float* Wh   = (const float*)d_in[12];
  const float* lb   = (const float*)d_in[13];
  const float* Wp   = (const float*)d_in[14];
  const float* bp   = (const float*)d_in[15];
  const float* lng  = (const float*)d_in[16];
  const float* lnb  = (const float*)d_in[17];
  const float* Wo   = (const float*)d_in[18];
  const float* bo   = (const float*)d_in[19];
  float* out = (float*)d_out;
  float* ws  = (float*)d_ws;

  float* gates = ws;                       // 65536
  float* hbuf  = gates + 65536;            // 16384
  float* pvec  = hbuf  + 16384;            // 16384 (stride 512, 471 used)
  float* alloc = pvec  + 16384;            // 32768
  float* wwb   = alloc + 32768;            // 32768
  float* memn  = wwb   + 32768;            // 2097152
  float* inorm = memn  + 2097152;          // 32768
  float* T1    = inorm + 32768;            // 131072
  float* T2    = T1    + 131072;           // 131072
  float* S1    = T2    + 131072;           // 131072
  float* S2    = S1    + 131072;           // 131072
  float* spsw  = S2    + 131072;           // 256
  float* readsb= spsw  + 256;              // 8192

  k_gates  <<<dim3(32),     dim3(256),  0, stream>>>(X, prvr, h0, Wx, Wh, lb, gates);
  k_lstm_ep<<<dim3(64),     dim3(256),  0, stream>>>(gates, c0, hbuf);
  k_pvec   <<<dim3(32),     dim3(512),  0, stream>>>(hbuf, emb, Wp, bp, lng, lnb, pvec);
  k_alloc  <<<dim3(32),     dim3(1024), 0, stream>>>(pvec, rwp, wwp, up, alloc);
  k_ww     <<<dim3(32),     dim3(1024), 0, stream>>>(pvec, mem, alloc, prec, rwp, wwb, spsw);
  k_memupd <<<dim3(16,32),  dim3(256),  0, stream>>>(pvec, mem, wwb, memn, inorm);
  k_zero   <<<dim3(1024),   dim3(256),  0, stream>>>(T1, 262144);   // zeros T1+T2 (contiguous)
  k_bwdcols<<<dim3(16,32),  dim3(1024), 0, stream>>>(links, rwp, wwb, T1, T2);
  k_fwdrows<<<dim3(16,32),  dim3(256),  0, stream>>>(links, rwp, wwb, S1, S2);
  k_read   <<<dim3(32),     dim3(1024), 0, stream>>>(pvec, memn, inorm, links, rwp, prec,
                                                     wwb, T1, T2, S1, S2, spsw, readsb);
  k_out    <<<dim3(32),     dim3(256),  0, stream>>>(hbuf, emb, readsb, Wo, bo, out);
}

// Round 2
// 309.513 us; speedup vs baseline: 1.5745x; 1.5745x over previous
//
#include <hip/hip_runtime.h>
#include <math.h>

#define Bb 32
#define Nn 1024
#define Mm 64
#define Rr 4
#define Hh 512
#define NINq 256
#define Pp 471
#define EPSN 1e-8f

__device__ __forceinline__ float sigm(float x){ return 1.0f/(1.0f+expf(-x)); }

// ---------------- xcat = [X | prev_read | h0]  (32 x 1024) ----------------
__global__ void k_xcat(const float* __restrict__ X, const float* __restrict__ pr,
                       const float* __restrict__ h0, float* __restrict__ xcat)
{
  int idx = blockIdx.x*blockDim.x + threadIdx.x;
  if (idx >= Bb*1024) return;
  int b = idx >> 10, t = idx & 1023;
  float v;
  if (t < 256) v = X[b*NINq + t];
  else if (t < 512) v = pr[b*(Rr*Mm) + t-256];
  else v = h0[b*Hh + t-512];
  xcat[idx] = v;
}

// ---------------- init out[32 x ncols] (stride ldo) with bias ----------------
__global__ void k_initb(float* __restrict__ out, const float* __restrict__ bias,
                        int ncols, int ldo)
{
  int b = blockIdx.y;
  int c = blockIdx.x*blockDim.x + threadIdx.x;
  if (c < ncols) out[b*ldo + c] = bias[c];
}

// ---------------- generic split-K atomic GEMM ----------------
// out[32 x ncols] += A[32 x lda(K)] @ W[K x ncols]; K covered by grid.y chunks of 64.
// W rows come from W1 for k<ksplit else W2 (both leading-dim ldw).
// block 256 = 64 cols x 4 bgroups of 8 batches.
__global__ __launch_bounds__(256) void k_gemm(
    const float* __restrict__ A, int lda,
    const float* __restrict__ W1, const float* __restrict__ W2, int ksplit,
    int ldw, int ncols, int ldo, float* __restrict__ out)
{
  __shared__ float lin[32][64];
  int tid = threadIdx.x;
  int col = blockIdx.x*64 + (tid & 63);
  int bg  = tid >> 6;
  int k0  = blockIdx.y*64;
#pragma unroll
  for (int q=0;q<8;q++){
    int idx = tid + 256*q;
    int bb = idx >> 6, kk = idx & 63;
    lin[bb][kk] = A[bb*lda + k0 + kk];
  }
  __syncthreads();
  if (col >= ncols) return;
  const float* Wr = (k0 < ksplit) ? (W1 + (size_t)k0*ldw)
                                  : (W2 + (size_t)(k0 - ksplit)*ldw);
  float acc[8];
#pragma unroll
  for (int i=0;i<8;i++) acc[i]=0.f;
  for (int kk=0; kk<64; ++kk){
    float wv = Wr[(size_t)kk*ldw + col];
#pragma unroll
    for (int bb=0; bb<8; ++bb) acc[bb] += wv * lin[bg*8+bb][kk];
  }
#pragma unroll
  for (int bb=0; bb<8; ++bb)
    atomicAdd(&out[(size_t)(bg*8+bb)*ldo + col], acc[bb]);
}

// ---------------- LSTM epilogue -> h ; also scatter h/emb into hcat, ocat ----------------
__global__ void k_lstm_ep(const float* __restrict__ gates, const float* __restrict__ c0,
                          const float* __restrict__ emb,
                          float* __restrict__ hcat, float* __restrict__ ocat)
{
  int idx = blockIdx.x*blockDim.x + threadIdx.x;
  if (idx >= Bb*Hh) return;
  int b = idx >> 9, j = idx & 511;
  const float* g = gates + b*2048;
  float gi = g[j], gf = g[j+512], gg = g[j+1024], go = g[j+1536];
  float c = sigm(gf)*c0[idx] + sigm(gi)*tanhf(gg);
  float h = sigm(go)*tanhf(c);
  float e = emb[idx];
  hcat[b*1024 + j]       = h;
  hcat[b*1024 + 512 + j] = e;
  ocat[b*1280 + j]       = h;
  ocat[b*1280 + 512 + j] = e;
}

// ---------------- LayerNorm in place on pvec (stride 512, 471 valid) ----------------
__global__ __launch_bounds__(512) void k_ln(
    const float* __restrict__ ln_g, const float* __restrict__ ln_b,
    float* __restrict__ pvec)
{
  __shared__ float red[8];
  int b = blockIdx.x, tid = threadIdx.x;
  float acc = (tid < Pp) ? pvec[b*512 + tid] : 0.f;
  float s = acc;
  for (int o=32;o;o>>=1) s += __shfl_xor(s,o,64);
  if ((tid&63)==0) red[tid>>6] = s;
  __syncthreads();
  if (tid < 8){ float xx = red[tid]; for (int o=4;o;o>>=1) xx += __shfl_xor(xx,o,64); if (!tid) red[0]=xx; }
  __syncthreads();
  float mu = red[0] / (float)Pp;
  __syncthreads();
  float d = (tid < Pp) ? (acc - mu) : 0.f;
  float s2 = d*d;
  for (int o=32;o;o>>=1) s2 += __shfl_xor(s2,o,64);
  if ((tid&63)==0) red[tid>>6] = s2;
  __syncthreads();
  if (tid < 8){ float xx = red[tid]; for (int o=4;o;o>>=1) xx += __shfl_xor(xx,o,64); if (!tid) red[0]=xx; }
  __syncthreads();
  float var = red[0] / (float)Pp;
  if (tid < Pp)
    pvec[b*512 + tid] = d / sqrtf(var + 1e-5f) * ln_g[tid] + ln_b[tid];
}

// ---------------- usage + allocation (bitonic argsort) ----------------
__global__ __launch_bounds__(1024) void k_alloc(
    const float* __restrict__ pvec, const float* __restrict__ rwp,
    const float* __restrict__ wwp, const float* __restrict__ up,
    float* __restrict__ alloc)
{
  __shared__ unsigned long long sk[1024];
  __shared__ float sf[1024];
  __shared__ float fg[4];
  int b = blockIdx.x, tid = threadIdx.x;
  if (tid < 4) fg[tid] = sigm(pvec[b*512 + 128 + tid]);
  __syncthreads();
  float psi = 1.f;
#pragma unroll
  for (int r=0;r<4;r++) psi *= 1.f - fg[r]*rwp[b*(Rr*Nn) + r*Nn + tid];
  float u = up[b*Nn+tid], w = wwp[b*Nn+tid];
  float usage = (u + w - u*w)*psi;               // >= 0 always
  sk[tid] = ((unsigned long long)__float_as_uint(usage) << 32) | (unsigned)tid;
  __syncthreads();
  for (int k=2; k<=1024; k<<=1)
    for (int j=k>>1; j>0; j>>=1) {
      int ixj = tid ^ j;
      if (ixj > tid) {
        unsigned long long a = sk[tid], c = sk[ixj];
        bool asc = ((tid & k) == 0);
        if ((a > c) == asc) { sk[tid]=c; sk[ixj]=a; }
      }
      __syncthreads();
    }
  unsigned long long key = sk[tid];
  float us = __uint_as_float((unsigned)(key >> 32));
  int order = (int)(key & 1023u);
  sf[tid] = us;
  for (int dd=1; dd<1024; dd<<=1) {
    __syncthreads();
    float p = (tid >= dd) ? sf[tid-dd] : 1.f;
    float cur = sf[tid];
    __syncthreads();
    sf[tid] = cur * p;
  }
  __syncthreads();
  alloc[b*Nn + order] = (1.f - us) * sf[tid];
}

// ---------------- write content -> ww, plus Sp/Sw scalars ----------------
__global__ __launch_bounds__(1024) void k_ww(
    const float* __restrict__ pvec, const float* __restrict__ mem,
    const float* __restrict__ alloc, const float* __restrict__ prec,
    const float* __restrict__ rwp, float* __restrict__ wwb, float* __restrict__ spsw)
{
  __shared__ float kdir[64];
  __shared__ float sim[1024];
  __shared__ float red[16];
  __shared__ float red8[16][8];
  __shared__ float scal[4];
  int b = blockIdx.x, tid = threadIdx.x;
  int wv = tid >> 6, lane = tid & 63;
  const float* pv = pvec + b*512;
  if (tid < 64) kdir[tid] = pv[146 + tid];
  if (wv == 0) {
    float v = kdir[lane];
    float s = v*v;
    for (int o=32;o;o>>=1) s += __shfl_xor(s,o,64);
    kdir[lane] = v / (sqrtf(s) + EPSN);
  }
  if (tid == 0) {
    scal[1] = 1.f + log1pf(expf(pv[210]));  // write strength
    scal[2] = sigm(pv[132]);                // alloc gate
    scal[3] = sigm(pv[133]);                // write gate
  }
  __syncthreads();
  float beta = scal[1], ag = scal[2], wg = scal[3];
  for (int t=0; t<64; ++t) {
    int n = wv*64 + t;
    float v = mem[(b*Nn + n)*Mm + lane];
    float d = v * kdir[lane];
    float s2 = v*v;
    for (int o=32;o;o>>=1){ d += __shfl_xor(d,o,64); s2 += __shfl_xor(s2,o,64); }
    if (lane == 0) sim[n] = beta * (d / (sqrtf(s2) + EPSN));
  }
  __syncthreads();
  float v = sim[tid];
  float m_ = v;
  for (int o=32;o;o>>=1) m_ = fmaxf(m_, __shfl_xor(m_,o,64));
  if (lane==0) red[wv] = m_;
  __syncthreads();
  if (tid < 16){ float x = red[tid]; for (int o=8;o;o>>=1) x = fmaxf(x,__shfl_xor(x,o,64)); if (!tid) red[0]=x; }
  __syncthreads();
  float gmax = red[0];
  __syncthreads();
  float e = expf(v - gmax);
  float ss = e;
  for (int o=32;o;o>>=1) ss += __shfl_xor(ss,o,64);
  if (lane==0) red[wv] = ss;
  __syncthreads();
  if (tid < 16){ float x = red[tid]; for (int o=8;o;o>>=1) x += __shfl_xor(x,o,64); if (!tid) red[0]=x; }
  __syncthreads();
  float wcn = e / red[0];
  __syncthreads();
  float an = alloc[b*Nn + tid];
  float wwn = wg * (ag*an + (1.f-ag)*wcn);
  wwb[b*Nn + tid] = wwn;
  float p = prec[b*Nn + tid];
#pragma unroll
  for (int r=0;r<4;r++){
    float a = rwp[b*(Rr*Nn) + r*Nn + tid];
    float x1 = p*a, x2 = wwn*a;
    for (int o=32;o;o>>=1){ x1 += __shfl_xor(x1,o,64); x2 += __shfl_xor(x2,o,64); }
    if (lane==0){ red8[wv][r] = x1; red8[wv][4+r] = x2; }
  }
  __syncthreads();
  if (tid < 8) {
    float s = 0.f;
    for (int w2=0; w2<16; ++w2) s += red8[w2][tid];
    spsw[b*8 + tid] = s;   // [0..3]=Sp, [4..7]=Sw
  }
}

// ---------------- memory update + inverse norms ----------------
__global__ __launch_bounds__(256) void k_memupd(
    const float* __restrict__ pvec, const float* __restrict__ mem,
    const float* __restrict__ wwb, float* __restrict__ memn, float* __restrict__ inorm)
{
  __shared__ float ev[64], wvv[64];
  int b = blockIdx.y, tid = threadIdx.x;
  int wv = tid>>6, lane = tid&63;
  const float* pv = pvec + b*512;
  if (tid < 64) { wvv[tid] = pv[tid]; ev[tid] = sigm(pv[64+tid]); }
  __syncthreads();
  for (int t=0;t<16;++t){
    int n = blockIdx.x*64 + wv*16 + t;
    float wwn = wwb[b*Nn + n];
    float v = mem[(b*Nn+n)*Mm + lane];
    float nv = v*(1.f - wwn*ev[lane]) + wwn*wvv[lane];
    memn[(b*Nn+n)*Mm + lane] = nv;
    float s = nv*nv;
    for (int o=32;o;o>>=1) s += __shfl_xor(s,o,64);
    if (lane==0) inorm[b*Nn+n] = 1.f/(sqrtf(s)+EPSN);
  }
}

__global__ void k_zero(float* __restrict__ p, int n){
  int i = blockIdx.x*blockDim.x + threadIdx.x;
  if (i < n) p[i] = 0.f;
}

// ---------------- column dots of links (for bwd) ----------------
__global__ __launch_bounds__(1024) void k_bwdcols(
    const float* __restrict__ links, const float* __restrict__ rwp,
    const float* __restrict__ wwb, float* __restrict__ T1, float* __restrict__ T2)
{
  __shared__ float a4[4][64], wa4[4][64];
  int b = blockIdx.y, j0 = blockIdx.x*64, tid = threadIdx.x;
  if (tid < 256) {
    int r = tid>>6, jj = tid&63;
    float a = rwp[b*(Rr*Nn) + r*Nn + j0+jj];
    a4[r][jj] = a;
    wa4[r][jj] = a * wwb[b*Nn + j0+jj];
  }
  __syncthreads();
  float t1[4]={0,0,0,0}, t2[4]={0,0,0,0};
  const float* Lb = links + (size_t)b*Nn*Nn;
  for (int jj=0; jj<64; ++jj) {
    float v = Lb[(size_t)(j0+jj)*Nn + tid];
#pragma unroll
    for (int r=0;r<4;r++){ t1[r] += v*a4[r][jj]; t2[r] += v*wa4[r][jj]; }
  }
#pragma unroll
  for (int r=0;r<4;r++){
    atomicAdd(&T1[(b*4+r)*Nn + tid], t1[r]);
    atomicAdd(&T2[(b*4+r)*Nn + tid], t2[r]);
  }
}

// ---------------- row dots of links (for fwd) ----------------
__global__ __launch_bounds__(256) void k_fwdrows(
    const float* __restrict__ links, const float* __restrict__ rwp,
    const float* __restrict__ wwb, float* __restrict__ S1, float* __restrict__ S2)
{
  __shared__ float a4[4096], wa4[4096];
  int b = blockIdx.y, i0 = blockIdx.x*64, tid = threadIdx.x;
  int wv = tid>>6, lane = tid&63;
  for (int q=0;q<16;q++){
    int idx = tid + 256*q;
    float a = rwp[b*(Rr*Nn) + idx];
    a4[idx] = a;
    wa4[idx] = a * wwb[b*Nn + (idx & 1023)];
  }
  __syncthreads();
  const float* Lb = links + (size_t)b*Nn*Nn;
  for (int t=0;t<16;++t){
    int i = i0 + wv*16 + t;
    float s1[4]={0,0,0,0}, s2[4]={0,0,0,0};
    const float* Lr = Lb + (size_t)i*Nn;
    for (int it=0; it<16; ++it){
      int j = lane + it*64;
      float v = Lr[j];
#pragma unroll
      for (int r=0;r<4;r++){ s1[r] += v*a4[r*Nn+j]; s2[r] += v*wa4[r*Nn+j]; }
    }
#pragma unroll
    for (int r=0;r<4;r++){
      float x1=s1[r], x2=s2[r];
      for (int o=32;o;o>>=1){ x1 += __shfl_xor(x1,o,64); x2 += __shfl_xor(x2,o,64); }
      if (lane==0){ S1[(b*4+r)*Nn + i] = x1; S2[(b*4+r)*Nn + i] = x2; }
    }
  }
}

// ---------------- read content + rw combine + reads GEMV (into ocat) ----------------
__global__ __launch_bounds__(1024) void k_read(
    const float* __restrict__ pvec, const float* __restrict__ memn,
    const float* __restrict__ inorm, const float* __restrict__ links,
    const float* __restrict__ rwp, const float* __restrict__ prec,
    const float* __restrict__ wwb, const float* __restrict__ T1,
    const float* __restrict__ T2, const float* __restrict__ S1,
    const float* __restrict__ S2, const float* __restrict__ spsw,
    float* __restrict__ ocat)
{
  __shared__ float kdir[4][64];
  __shared__ float sim[4][1024];
  __shared__ float wws[1024];
  __shared__ float red[16];
  __shared__ float rm[4][3];
  __shared__ float beta[4];
  __shared__ float rp[16][64];
  int b = blockIdx.x, tid = threadIdx.x;
  int wv = tid>>6, lane = tid&63;
  const float* pv = pvec + b*512;
  if (wv < 4) {
    float v = pv[211 + wv*64 + lane];
    float s = v*v;
    for (int o=32;o;o>>=1) s += __shfl_xor(s,o,64);
    kdir[wv][lane] = v/(sqrtf(s)+EPSN);
    if (lane==0) beta[wv] = 1.f + log1pf(expf(pv[467+wv]));
  }
  if (tid < 4) {
    float x0 = pv[134 + tid*3], x1 = pv[134+tid*3+1], x2 = pv[134+tid*3+2];
    float mx = fmaxf(x0, fmaxf(x1,x2));
    float e0 = expf(x0-mx), e1=expf(x1-mx), e2=expf(x2-mx);
    float s = e0+e1+e2;
    rm[tid][0]=e0/s; rm[tid][1]=e1/s; rm[tid][2]=e2/s;
  }
  wws[tid] = wwb[b*Nn + tid];
  __syncthreads();
  for (int t=0;t<64;++t){
    int n = wv*64 + t;
    float v = memn[(b*Nn+n)*Mm + lane];
    float d0=v*kdir[0][lane], d1=v*kdir[1][lane], d2=v*kdir[2][lane], d3=v*kdir[3][lane];
    for (int o=32;o;o>>=1){ d0+=__shfl_xor(d0,o,64); d1+=__shfl_xor(d1,o,64); d2+=__shfl_xor(d2,o,64); d3+=__shfl_xor(d3,o,64); }
    if (lane==0){
      float inv = inorm[b*Nn+n];
      sim[0][n]=beta[0]*d0*inv; sim[1][n]=beta[1]*d1*inv;
      sim[2][n]=beta[2]*d2*inv; sim[3][n]=beta[3]*d3*inv;
    }
  }
  __syncthreads();
  float Lii = links[(size_t)b*Nn*Nn + (size_t)tid*Nn + tid];
  float w_n = wws[tid];
  float p_n = prec[b*Nn + tid];
  for (int r=0;r<4;r++){
    float v = sim[r][tid];
    float m_ = v;
    for (int o=32;o;o>>=1) m_ = fmaxf(m_, __shfl_xor(m_,o,64));
    if (lane==0) red[wv]=m_;
    __syncthreads();
    if (tid<16){ float x=red[tid]; for(int o=8;o;o>>=1) x=fmaxf(x,__shfl_xor(x,o,64)); if(!tid) red[0]=x; }
    __syncthreads();
    float gmax = red[0];
    __syncthreads();
    float e = expf(v-gmax);
    float s = e;
    for (int o=32;o;o>>=1) s += __shfl_xor(s,o,64);
    if (lane==0) red[wv]=s;
    __syncthreads();
    if (tid<16){ float x=red[tid]; for(int o=8;o;o>>=1) x+=__shfl_xor(x,o,64); if(!tid) red[0]=x; }
    __syncthreads();
    float rc = e/red[0];
    __syncthreads();
    float a = rwp[b*(Rr*Nn)+r*Nn+tid];
    float s1v = S1[(b*4+r)*Nn+tid], s2v = S2[(b*4+r)*Nn+tid];
    float t1v = T1[(b*4+r)*Nn+tid], t2v = T2[(b*4+r)*Nn+tid];
    float Spr = spsw[b*8+r], Swr = spsw[b*8+4+r];
    float fwd = (1.f-w_n)*(s1v - Lii*a) - (s2v - Lii*w_n*a) + w_n*(Spr - p_n*a);
    float bwd = (1.f-w_n)*(t1v - Lii*a) - (t2v - w_n*Lii*a) + p_n*(Swr - w_n*a);
    sim[r][tid] = rm[r][1]*rc + rm[r][0]*bwd + rm[r][2]*fwd;   // rw
  }
  __syncthreads();
  int r = wv >> 2, ch = wv & 3;
  float acc = 0.f;
  for (int t=0;t<256;++t){
    int n = ch*256 + t;
    acc += sim[r][n] * memn[(b*Nn+n)*Mm + lane];
  }
  rp[wv][lane] = acc;
  __syncthreads();
  if (tid < 256) {
    int rr = tid>>6, m = tid&63;
    float s = rp[rr*4+0][m]+rp[rr*4+1][m]+rp[rr*4+2][m]+rp[rr*4+3][m];
    ocat[b*1280 + 1024 + rr*64 + m] = s;
  }
}

extern "C" void kernel_launch(void* const* d_in, const int* in_sizes, int n_in,
                              void* d_out, int out_size, void* d_ws, size_t ws_size,
                              hipStream_t stream)
{
  (void)in_sizes; (void)n_in; (void)out_size; (void)ws_size;
  const float* X    = (const float*)d_in[0];
  const float* emb  = (const float*)d_in[1];
  const float* mem  = (const float*)d_in[2];
  const float* prvr = (const float*)d_in[3];
  const float* h0   = (const float*)d_in[4];
  const float* c0   = (const float*)d_in[5];
  const float* rwp  = (const float*)d_in[6];
  const float* wwp  = (const float*)d_in[7];
  const float* up   = (const float*)d_in[8];
  const float* prec = (const float*)d_in[9];
  const float* links= (const float*)d_in[10];
  const float* Wx   = (const float*)d_in[11];
  const float* Wh   = (const float*)d_in[12];
  const float* lb   = (const float*)d_in[13];
  const float* Wp   = (const float*)d_in[14];
  const float* bp   = (const float*)d_in[15];
  const float* lng  = (const float*)d_in[16];
  const float* lnb  = (const float*)d_in[17];
  const float* Wo   = (const float*)d_in[18];
  const float* bo   = (const float*)d_in[19];
  float* out = (float*)d_out;
  float* ws  = (float*)d_ws;

  // persistent-lifetime buffers
  float* memn  = ws;                       // 2097152
  float* inorm = memn  + 2097152;          // 32768
  float* T1    = inorm + 32768;            // 131072
  float* T2    = T1    + 131072;           // 131072
  float* S1    = T2    + 131072;           // 131072
  float* S2    = S1    + 131072;           // 131072
  float* pvec  = S2    + 131072;           // 16384 (stride 512, 471 used)
  float* alloc = pvec  + 16384;            // 32768
  float* wwb   = alloc + 32768;            // 32768
  float* ocat  = wwb   + 32768;            // 40960  [h|emb|reads]
  float* spsw  = ocat  + 40960;            // 256
  // short-lifetime aliases (all dead before k_zero zeroes T1/T2, and before
  // k_fwdrows writes S1/S2 — stream order guarantees no overlap in time)
  float* xcat  = T1;                       // 32768  [X|prev_read|h0]
  float* hcat  = T1 + 32768;               // 32768  [h|emb]
  float* gates = S1;                       // 65536

  k_xcat   <<<dim3(128),    dim3(256),  0, stream>>>(X, prvr, h0, xcat);
  k_initb  <<<dim3(8,32),   dim3(256),  0, stream>>>(gates, lb, 2048, 2048);
  k_gemm   <<<dim3(32,16),  dim3(256),  0, stream>>>(xcat, 1024, Wx, Wh, 512, 2048, 2048, 2048, gates);
  k_lstm_ep<<<dim3(64),     dim3(256),  0, stream>>>(gates, c0, emb, hcat, ocat);
  k_initb  <<<dim3(2,32),   dim3(256),  0, stream>>>(pvec, bp, 471, 512);
  k_gemm   <<<dim3(8,16),   dim3(256),  0, stream>>>(hcat, 1024, Wp, Wp, 1<<30, 471, 471, 512, pvec);
  k_ln     <<<dim3(32),     dim3(512),  0, stream>>>(lng, lnb, pvec);
  k_alloc  <<<dim3(32),     dim3(1024), 0, stream>>>(pvec, rwp, wwp, up, alloc);
  k_ww     <<<dim3(32),     dim3(1024), 0, stream>>>(pvec, mem, alloc, prec, rwp, wwb, spsw);
  k_memupd <<<dim3(16,32),  dim3(256),  0, stream>>>(pvec, mem, wwb, memn, inorm);
  k_zero   <<<dim3(1024),   dim3(256),  0, stream>>>(T1, 262144);   // zeros T1+T2 (contiguous)
  k_bwdcols<<<dim3(16,32),  dim3(1024), 0, stream>>>(links, rwp, wwb, T1, T2);
  k_fwdrows<<<dim3(16,32),  dim3(256),  0, stream>>>(links, rwp, wwb, S1, S2);
  k_read   <<<dim3(32),     dim3(1024), 0, stream>>>(pvec, memn, inorm, links, rwp, prec,
                                                     wwb, T1, T2, S1, S2, spsw, ocat);
  k_initb  <<<dim3(1,32),   dim3(256),  0, stream>>>(out, bo, 256, 256);
  k_gemm   <<<dim3(4,20),   dim3(256),  0, stream>>>(ocat, 1280, Wo, Wo, 1<<30, 256, 256, 256, out);
}

// Round 3
// 212.235 us; speedup vs baseline: 2.2962x; 1.4584x over previous
//
#include <hip/hip_runtime.h>
#include <math.h>

#define Bb 32
#define Nn 1024
#define Mm 64
#define Rr 4
#define Hh 512
#define NINq 256
#define Pp 471
#define EPSN 1e-8f

__device__ __forceinline__ float sigm(float x){ return 1.0f/(1.0f+expf(-x)); }

// ---------------- xcat = [X | prev_read | h0]  (32 x 1024) ----------------
__global__ void k_xcat(const float* __restrict__ X, const float* __restrict__ pr,
                       const float* __restrict__ h0, float* __restrict__ xcat)
{
  int idx = blockIdx.x*blockDim.x + threadIdx.x;
  if (idx >= Bb*1024) return;
  int b = idx >> 10, t = idx & 1023;
  float v;
  if (t < 256) v = X[b*NINq + t];
  else if (t < 512) v = pr[b*(Rr*Mm) + t-256];
  else v = h0[b*Hh + t-512];
  xcat[idx] = v;
}

// ---------------- init out[32 x ncols] (stride ldo) with bias ----------------
__global__ void k_initb(float* __restrict__ out, const float* __restrict__ bias,
                        int ncols, int ldo)
{
  int b = blockIdx.y;
  int c = blockIdx.x*blockDim.x + threadIdx.x;
  if (c < ncols) out[b*ldo + c] = bias[c];
}

// ---------------- generic split-K atomic GEMM ----------------
__global__ __launch_bounds__(256) void k_gemm(
    const float* __restrict__ A, int lda,
    const float* __restrict__ W1, const float* __restrict__ W2, int ksplit,
    int ldw, int ncols, int ldo, float* __restrict__ out)
{
  __shared__ float lin[32][64];
  int tid = threadIdx.x;
  int col = blockIdx.x*64 + (tid & 63);
  int bg  = tid >> 6;
  int k0  = blockIdx.y*64;
#pragma unroll
  for (int q=0;q<8;q++){
    int idx = tid + 256*q;
    int bb = idx >> 6, kk = idx & 63;
    lin[bb][kk] = A[bb*lda + k0 + kk];
  }
  __syncthreads();
  if (col >= ncols) return;
  const float* Wr = (k0 < ksplit) ? (W1 + (size_t)k0*ldw)
                                  : (W2 + (size_t)(k0 - ksplit)*ldw);
  float acc[8];
#pragma unroll
  for (int i=0;i<8;i++) acc[i]=0.f;
  for (int kk=0; kk<64; ++kk){
    float wv = Wr[(size_t)kk*ldw + col];
#pragma unroll
    for (int bb=0; bb<8; ++bb) acc[bb] += wv * lin[bg*8+bb][kk];
  }
#pragma unroll
  for (int bb=0; bb<8; ++bb)
    atomicAdd(&out[(size_t)(bg*8+bb)*ldo + col], acc[bb]);
}

// ---------------- LSTM epilogue -> h ; scatter h/emb into hcat/ocat; zero reads ----------------
__global__ void k_lstm_ep(const float* __restrict__ gates, const float* __restrict__ c0,
                          const float* __restrict__ emb,
                          float* __restrict__ hcat, float* __restrict__ ocat)
{
  int idx = blockIdx.x*blockDim.x + threadIdx.x;
  if (idx >= Bb*Hh) return;
  int b = idx >> 9, j = idx & 511;
  const float* g = gates + b*2048;
  float gi = g[j], gf = g[j+512], gg = g[j+1024], go = g[j+1536];
  float c = sigm(gf)*c0[idx] + sigm(gi)*tanhf(gg);
  float h = sigm(go)*tanhf(c);
  float e = emb[idx];
  hcat[b*1024 + j]       = h;
  hcat[b*1024 + 512 + j] = e;
  ocat[b*1280 + j]       = h;
  ocat[b*1280 + 512 + j] = e;
  if (j < 256) ocat[b*1280 + 1024 + j] = 0.f;   // reads section (atomicAdd target)
}

// ---------------- LayerNorm in place on pvec ----------------
__global__ __launch_bounds__(512) void k_ln(
    const float* __restrict__ ln_g, const float* __restrict__ ln_b,
    float* __restrict__ pvec)
{
  __shared__ float red[8];
  int b = blockIdx.x, tid = threadIdx.x;
  float acc = (tid < Pp) ? pvec[b*512 + tid] : 0.f;
  float s = acc;
  for (int o=32;o;o>>=1) s += __shfl_xor(s,o,64);
  if ((tid&63)==0) red[tid>>6] = s;
  __syncthreads();
  if (tid < 8){ float xx = red[tid]; for (int o=4;o;o>>=1) xx += __shfl_xor(xx,o,64); if (!tid) red[0]=xx; }
  __syncthreads();
  float mu = red[0] / (float)Pp;
  __syncthreads();
  float d = (tid < Pp) ? (acc - mu) : 0.f;
  float s2 = d*d;
  for (int o=32;o;o>>=1) s2 += __shfl_xor(s2,o,64);
  if ((tid&63)==0) red[tid>>6] = s2;
  __syncthreads();
  if (tid < 8){ float xx = red[tid]; for (int o=4;o;o>>=1) xx += __shfl_xor(xx,o,64); if (!tid) red[0]=xx; }
  __syncthreads();
  float var = red[0] / (float)Pp;
  if (tid < Pp)
    pvec[b*512 + tid] = d / sqrtf(var + 1e-5f) * ln_g[tid] + ln_b[tid];
}

// ---------------- usage + allocation (shfl bitonic argsort + shfl scan) ----------------
__global__ __launch_bounds__(1024) void k_alloc(
    const float* __restrict__ pvec, const float* __restrict__ rwp,
    const float* __restrict__ wwp, const float* __restrict__ up,
    float* __restrict__ alloc)
{
  __shared__ unsigned long long sk[1024];
  __shared__ float wsums[16];
  __shared__ float fg[4];
  int b = blockIdx.x, tid = threadIdx.x;
  int lane = tid & 63, wv = tid >> 6;
  if (tid < 4) fg[tid] = sigm(pvec[b*512 + 128 + tid]);
  __syncthreads();
  float psi = 1.f;
#pragma unroll
  for (int r=0;r<4;r++) psi *= 1.f - fg[r]*rwp[b*(Rr*Nn) + r*Nn + tid];
  float u = up[b*Nn+tid], w = wwp[b*Nn+tid];
  float usage = (u + w - u*w)*psi;               // >= 0 always
  unsigned long long key = ((unsigned long long)__float_as_uint(usage) << 32) | (unsigned)tid;
  // bitonic sort: intra-wave stages via shfl, cross-wave via LDS
  for (int k=2; k<=1024; k<<=1) {
    for (int j=k>>1; j>0; j>>=1) {
      bool lower = (tid & j) == 0;
      bool asc   = (tid & k) == 0;
      unsigned long long pk;
      if (j >= 64) {
        sk[tid] = key; __syncthreads();
        pk = sk[tid ^ j];
        __syncthreads();
      } else {
        pk = __shfl_xor(key, j, 64);
      }
      key = ((key < pk) == (lower == asc)) ? key : pk;
    }
  }
  float us = __uint_as_float((unsigned)(key >> 32));
  int order = (int)(key & 1023u);
  // inclusive cumprod scan
  float v = us;
#pragma unroll
  for (int d=1; d<64; d<<=1) {
    float p = __shfl_up(v, d, 64);
    if (lane >= d) v *= p;
  }
  if (lane == 63) wsums[wv] = v;
  __syncthreads();
  if (wv == 0) {
    float t = (lane < 16) ? wsums[lane] : 1.f;
#pragma unroll
    for (int d=1; d<16; d<<=1) {
      float p = __shfl_up(t, d, 64);
      if (lane >= d) t *= p;
    }
    if (lane < 16) wsums[lane] = t;
  }
  __syncthreads();
  float prefix = (wv > 0) ? wsums[wv-1] : 1.f;
  alloc[b*Nn + order] = (1.f - us) * (v * prefix);
}

// ---------------- write-key cosine sim vs OLD memory (parallel) ----------------
__global__ __launch_bounds__(256) void k_simw(
    const float* __restrict__ pvec, const float* __restrict__ mem,
    float* __restrict__ simw)
{
  __shared__ float kdir[64];
  __shared__ float sc[1];
  int b = blockIdx.y, tid = threadIdx.x;
  int wv = tid>>6, lane = tid&63;
  const float* pv = pvec + b*512;
  if (wv == 0) {
    float v = pv[146 + lane];
    float s = v*v;
    for (int o=32;o;o>>=1) s += __shfl_xor(s,o,64);
    kdir[lane] = v / (sqrtf(s) + EPSN);
    if (lane == 0) sc[0] = 1.f + log1pf(expf(pv[210]));
  }
  __syncthreads();
  float beta = sc[0];
  for (int t=0;t<16;++t){
    int n = blockIdx.x*64 + wv*16 + t;
    float v = mem[(b*Nn+n)*Mm + lane];
    float d = v*kdir[lane], s2 = v*v;
    for (int o=32;o;o>>=1){ d += __shfl_xor(d,o,64); s2 += __shfl_xor(s2,o,64); }
    if (lane == 0) simw[b*Nn+n] = beta * d / (sqrtf(s2) + EPSN);
  }
}

// ---------------- softmax(simw) + gates -> ww, plus Sp/Sw scalars ----------------
__global__ __launch_bounds__(1024) void k_ww2(
    const float* __restrict__ pvec, const float* __restrict__ simw,
    const float* __restrict__ alloc, const float* __restrict__ prec,
    const float* __restrict__ rwp, float* __restrict__ wwb, float* __restrict__ spsw)
{
  __shared__ float red[16];
  __shared__ float red8[16][8];
  __shared__ float scal[2];
  int b = blockIdx.x, tid = threadIdx.x;
  int wv = tid >> 6, lane = tid & 63;
  const float* pv = pvec + b*512;
  if (tid == 0) { scal[0] = sigm(pv[132]); scal[1] = sigm(pv[133]); }
  float v = simw[b*Nn + tid];
  float m_ = v;
  for (int o=32;o;o>>=1) m_ = fmaxf(m_, __shfl_xor(m_,o,64));
  if (lane==0) red[wv] = m_;
  __syncthreads();
  if (tid < 16){ float x = red[tid]; for (int o=8;o;o>>=1) x = fmaxf(x,__shfl_xor(x,o,64)); if (!tid) red[0]=x; }
  __syncthreads();
  float gmax = red[0];
  __syncthreads();
  float e = expf(v - gmax);
  float ss = e;
  for (int o=32;o;o>>=1) ss += __shfl_xor(ss,o,64);
  if (lane==0) red[wv] = ss;
  __syncthreads();
  if (tid < 16){ float x = red[tid]; for (int o=8;o;o>>=1) x += __shfl_xor(x,o,64); if (!tid) red[0]=x; }
  __syncthreads();
  float wcn = e / red[0];
  float ag = scal[0], wg = scal[1];
  float an = alloc[b*Nn + tid];
  float wwn = wg * (ag*an + (1.f-ag)*wcn);
  wwb[b*Nn + tid] = wwn;
  float p = prec[b*Nn + tid];
#pragma unroll
  for (int r=0;r<4;r++){
    float a = rwp[b*(Rr*Nn) + r*Nn + tid];
    float x1 = p*a, x2 = wwn*a;
    for (int o=32;o;o>>=1){ x1 += __shfl_xor(x1,o,64); x2 += __shfl_xor(x2,o,64); }
    if (lane==0){ red8[wv][r] = x1; red8[wv][4+r] = x2; }
  }
  __syncthreads();
  if (tid < 8) {
    float s = 0.f;
    for (int w2=0; w2<16; ++w2) s += red8[w2][tid];
    spsw[b*8 + tid] = s;   // [0..3]=Sp, [4..7]=Sw
  }
}

// ---------------- memory update + fused read-key sims ----------------
__global__ __launch_bounds__(256) void k_memupd(
    const float* __restrict__ pvec, const float* __restrict__ mem,
    const float* __restrict__ wwb, float* __restrict__ memn, float* __restrict__ simr)
{
  __shared__ float ev[64], wvv[64];
  __shared__ float kdir[4][64];
  __shared__ float beta[4];
  int b = blockIdx.y, tid = threadIdx.x;
  int wv = tid>>6, lane = tid&63;
  const float* pv = pvec + b*512;
  {
    float kv = pv[211 + wv*64 + lane];
    float s = kv*kv;
    for (int o=32;o;o>>=1) s += __shfl_xor(s,o,64);
    kdir[wv][lane] = kv/(sqrtf(s)+EPSN);
    if (lane==0) beta[wv] = 1.f + log1pf(expf(pv[467+wv]));
  }
  if (tid < 64) { wvv[tid] = pv[tid]; ev[tid] = sigm(pv[64+tid]); }
  __syncthreads();
  for (int t=0;t<16;++t){
    int n = blockIdx.x*64 + wv*16 + t;
    float wwn = wwb[b*Nn + n];
    float v = mem[(b*Nn+n)*Mm + lane];
    float nv = v*(1.f - wwn*ev[lane]) + wwn*wvv[lane];
    memn[(b*Nn+n)*Mm + lane] = nv;
    float s2 = nv*nv;
    float d0 = nv*kdir[0][lane], d1 = nv*kdir[1][lane];
    float d2 = nv*kdir[2][lane], d3 = nv*kdir[3][lane];
    for (int o=32;o;o>>=1){
      s2 += __shfl_xor(s2,o,64);
      d0 += __shfl_xor(d0,o,64); d1 += __shfl_xor(d1,o,64);
      d2 += __shfl_xor(d2,o,64); d3 += __shfl_xor(d3,o,64);
    }
    if (lane==0){
      float inv = 1.f/(sqrtf(s2)+EPSN);
      simr[(b*4+0)*Nn+n] = beta[0]*d0*inv;
      simr[(b*4+1)*Nn+n] = beta[1]*d1*inv;
      simr[(b*4+2)*Nn+n] = beta[2]*d2*inv;
      simr[(b*4+3)*Nn+n] = beta[3]*d3*inv;
    }
  }
}

__global__ void k_zero(float* __restrict__ p, int n){
  int i = blockIdx.x*blockDim.x + threadIdx.x;
  if (i < n) p[i] = 0.f;
}

// ---------------- column dots of links (for bwd) ----------------
__global__ __launch_bounds__(1024) void k_bwdcols(
    const float* __restrict__ links, const float* __restrict__ rwp,
    const float* __restrict__ wwb, float* __restrict__ T1, float* __restrict__ T2)
{
  __shared__ float a4[4][64], wa4[4][64];
  int b = blockIdx.y, j0 = blockIdx.x*64, tid = threadIdx.x;
  if (tid < 256) {
    int r = tid>>6, jj = tid&63;
    float a = rwp[b*(Rr*Nn) + r*Nn + j0+jj];
    a4[r][jj] = a;
    wa4[r][jj] = a * wwb[b*Nn + j0+jj];
  }
  __syncthreads();
  float t1[4]={0,0,0,0}, t2[4]={0,0,0,0};
  const float* Lb = links + (size_t)b*Nn*Nn;
  for (int jj=0; jj<64; ++jj) {
    float v = Lb[(size_t)(j0+jj)*Nn + tid];
#pragma unroll
    for (int r=0;r<4;r++){ t1[r] += v*a4[r][jj]; t2[r] += v*wa4[r][jj]; }
  }
#pragma unroll
  for (int r=0;r<4;r++){
    atomicAdd(&T1[(b*4+r)*Nn + tid], t1[r]);
    atomicAdd(&T2[(b*4+r)*Nn + tid], t2[r]);
  }
}

// ---------------- row dots of links (for fwd) + diagonal extraction ----------------
__global__ __launch_bounds__(256) void k_fwdrows(
    const float* __restrict__ links, const float* __restrict__ rwp,
    const float* __restrict__ wwb, float* __restrict__ S1, float* __restrict__ S2,
    float* __restrict__ diag)
{
  __shared__ float a4[4096], wa4[4096];
  int b = blockIdx.y, i0 = blockIdx.x*64, tid = threadIdx.x;
  int wv = tid>>6, lane = tid&63;
  for (int q=0;q<16;q++){
    int idx = tid + 256*q;
    float a = rwp[b*(Rr*Nn) + idx];
    a4[idx] = a;
    wa4[idx] = a * wwb[b*Nn + (idx & 1023)];
  }
  __syncthreads();
  const float* Lb = links + (size_t)b*Nn*Nn;
  for (int t=0;t<16;++t){
    int i = i0 + wv*16 + t;
    float s1[4]={0,0,0,0}, s2[4]={0,0,0,0};
    const float* Lr = Lb + (size_t)i*Nn;
    for (int it=0; it<16; ++it){
      int j = lane + it*64;
      float v = Lr[j];
      if (j == i) diag[b*Nn + i] = v;
#pragma unroll
      for (int r=0;r<4;r++){ s1[r] += v*a4[r*Nn+j]; s2[r] += v*wa4[r*Nn+j]; }
    }
#pragma unroll
    for (int r=0;r<4;r++){
      float x1=s1[r], x2=s2[r];
      for (int o=32;o;o>>=1){ x1 += __shfl_xor(x1,o,64); x2 += __shfl_xor(x2,o,64); }
      if (lane==0){ S1[(b*4+r)*Nn + i] = x1; S2[(b*4+r)*Nn + i] = x2; }
    }
  }
}

// ---------------- per-(b,r): softmax(simr) + combine -> rw (in place) ----------------
__global__ __launch_bounds__(1024) void k_rsoft(
    const float* __restrict__ pvec, const float* __restrict__ rwp,
    const float* __restrict__ prec, const float* __restrict__ wwb,
    const float* __restrict__ T1, const float* __restrict__ T2,
    const float* __restrict__ S1, const float* __restrict__ S2,
    const float* __restrict__ spsw, const float* __restrict__ diag,
    float* __restrict__ simr)
{
  __shared__ float red[16];
  __shared__ float rm3[3];
  int b = blockIdx.x, r = blockIdx.y, tid = threadIdx.x;
  int wv = tid>>6, lane = tid&63;
  const float* pv = pvec + b*512;
  if (tid == 0) {
    float x0 = pv[134+r*3], x1 = pv[134+r*3+1], x2 = pv[134+r*3+2];
    float mx = fmaxf(x0, fmaxf(x1,x2));
    float e0 = expf(x0-mx), e1 = expf(x1-mx), e2 = expf(x2-mx);
    float s = e0+e1+e2;
    rm3[0]=e0/s; rm3[1]=e1/s; rm3[2]=e2/s;
  }
  float v = simr[(b*4+r)*Nn + tid];
  float m_ = v;
  for (int o=32;o;o>>=1) m_ = fmaxf(m_, __shfl_xor(m_,o,64));
  if (lane==0) red[wv]=m_;
  __syncthreads();
  if (tid<16){ float x=red[tid]; for(int o=8;o;o>>=1) x=fmaxf(x,__shfl_xor(x,o,64)); if(!tid) red[0]=x; }
  __syncthreads();
  float gmax = red[0];
  __syncthreads();
  float e = expf(v-gmax);
  float s = e;
  for (int o=32;o;o>>=1) s += __shfl_xor(s,o,64);
  if (lane==0) red[wv]=s;
  __syncthreads();
  if (tid<16){ float x=red[tid]; for(int o=8;o;o>>=1) x+=__shfl_xor(x,o,64); if(!tid) red[0]=x; }
  __syncthreads();
  float rc = e/red[0];
  float w_n = wwb[b*Nn + tid];
  float p_n = prec[b*Nn + tid];
  float a = rwp[b*(Rr*Nn)+r*Nn+tid];
  float Lii = diag[b*Nn + tid];
  float s1v = S1[(b*4+r)*Nn+tid], s2v = S2[(b*4+r)*Nn+tid];
  float t1v = T1[(b*4+r)*Nn+tid], t2v = T2[(b*4+r)*Nn+tid];
  float Spr = spsw[b*8+r], Swr = spsw[b*8+4+r];
  float fwd = (1.f-w_n)*(s1v - Lii*a) - (s2v - Lii*w_n*a) + w_n*(Spr - p_n*a);
  float bwd = (1.f-w_n)*(t1v - Lii*a) - (t2v - w_n*Lii*a) + p_n*(Swr - w_n*a);
  simr[(b*4+r)*Nn + tid] = rm3[1]*rc + rm3[0]*bwd + rm3[2]*fwd;   // rw
}

// ---------------- reads = rw @ memn  (atomic n-split) ----------------
__global__ __launch_bounds__(256) void k_rgemv(
    const float* __restrict__ simr, const float* __restrict__ memn,
    float* __restrict__ ocat)
{
  int b = blockIdx.y, ch = blockIdx.x, tid = threadIdx.x;
  int r = tid>>6, m = tid&63;
  float acc = 0.f;
#pragma unroll 8
  for (int t=0;t<128;++t){
    int n = ch*128 + t;
    acc += simr[(b*4+r)*Nn + n] * memn[(b*Nn+n)*Mm + m];
  }
  atomicAdd(&ocat[b*1280 + 1024 + r*64 + m], acc);
}

extern "C" void kernel_launch(void* const* d_in, const int* in_sizes, int n_in,
                              void* d_out, int out_size, void* d_ws, size_t ws_size,
                              hipStream_t stream)
{
  (void)in_sizes; (void)n_in; (void)out_size; (void)ws_size;
  const float* X    = (const float*)d_in[0];
  const float* emb  = (const float*)d_in[1];
  const float* mem  = (const float*)d_in[2];
  const float* prvr = (const float*)d_in[3];
  const float* h0   = (const float*)d_in[4];
  const float* c0   = (const float*)d_in[5];
  const float* rwp  = (const float*)d_in[6];
  const float* wwp  = (const float*)d_in[7];
  const float* up   = (const float*)d_in[8];
  const float* prec = (const float*)d_in[9];
  const float* links= (const float*)d_in[10];
  const float* Wx   = (const float*)d_in[11];
  const float* Wh   = (const float*)d_in[12];
  const float* lb   = (const float*)d_in[13];
  const float* Wp   = (const float*)d_in[14];
  const float* bp   = (const float*)d_in[15];
  const float* lng  = (const float*)d_in[16];
  const float* lnb  = (const float*)d_in[17];
  const float* Wo   = (const float*)d_in[18];
  const float* bo   = (const float*)d_in[19];
  float* out = (float*)d_out;
  float* ws  = (float*)d_ws;

  // persistent buffers
  float* memn  = ws;                       // 2097152
  float* T1    = memn  + 2097152;          // 131072
  float* T2    = T1    + 131072;           // 131072
  float* S1    = T2    + 131072;           // 131072
  float* S2    = S1    + 131072;           // 131072
  float* pvec  = S2    + 131072;           // 16384 (stride 512, 471 used)
  float* alloc = pvec  + 16384;            // 32768
  float* wwb   = alloc + 32768;            // 32768
  float* ocat  = wwb   + 32768;            // 40960  [h|emb|reads]
  float* spsw  = ocat  + 40960;            // 256
  float* simr  = spsw  + 256;              // 131072 (then rw in place)
  float* diag  = simr  + 131072;           // 32768
  // short-lifetime aliases (dead before their hosts are written):
  float* xcat  = T1;                       // dead after k_gemm(gates)
  float* hcat  = T1 + 32768;               // dead after k_gemm(para)
  float* gates = S1;                       // dead after k_lstm_ep
  float* simw  = S1;                       // written k_simw, dead after k_ww2 (before k_fwdrows)

  k_xcat   <<<dim3(128),    dim3(256),  0, stream>>>(X, prvr, h0, xcat);
  k_initb  <<<dim3(8,32),   dim3(256),  0, stream>>>(gates, lb, 2048, 2048);
  k_gemm   <<<dim3(32,16),  dim3(256),  0, stream>>>(xcat, 1024, Wx, Wh, 512, 2048, 2048, 2048, gates);
  k_lstm_ep<<<dim3(64),     dim3(256),  0, stream>>>(gates, c0, emb, hcat, ocat);
  k_initb  <<<dim3(2,32),   dim3(256),  0, stream>>>(pvec, bp, 471, 512);
  k_gemm   <<<dim3(8,16),   dim3(256),  0, stream>>>(hcat, 1024, Wp, Wp, 1<<30, 471, 471, 512, pvec);
  k_ln     <<<dim3(32),     dim3(512),  0, stream>>>(lng, lnb, pvec);
  k_alloc  <<<dim3(32),     dim3(1024), 0, stream>>>(pvec, rwp, wwp, up, alloc);
  k_simw   <<<dim3(16,32),  dim3(256),  0, stream>>>(pvec, mem, simw);
  k_ww2    <<<dim3(32),     dim3(1024), 0, stream>>>(pvec, simw, alloc, prec, rwp, wwb, spsw);
  k_memupd <<<dim3(16,32),  dim3(256),  0, stream>>>(pvec, mem, wwb, memn, simr);
  k_zero   <<<dim3(1024),   dim3(256),  0, stream>>>(T1, 262144);   // zeros T1+T2 (contiguous)
  k_bwdcols<<<dim3(16,32),  dim3(1024), 0, stream>>>(links, rwp, wwb, T1, T2);
  k_fwdrows<<<dim3(16,32),  dim3(256),  0, stream>>>(links, rwp, wwb, S1, S2, diag);
  k_rsoft  <<<dim3(32,4),   dim3(1024), 0, stream>>>(pvec, rwp, prec, wwb, T1, T2, S1, S2, spsw, diag, simr);
  k_rgemv  <<<dim3(8,32),   dim3(256),  0, stream>>>(simr, memn, ocat);
  k_initb  <<<dim3(1,32),   dim3(256),  0, stream>>>(out, bo, 256, 256);
  k_gemm   <<<dim3(4,20),   dim3(256),  0, stream>>>(ocat, 1280, Wo, Wo, 1<<30, 256, 256, 256, out);
}

// Round 4
// 183.025 us; speedup vs baseline: 2.6626x; 1.1596x over previous
//
#include <hip/hip_runtime.h>
#include <math.h>

#define Bb 32
#define Nn 1024
#define Mm 64
#define Rr 4
#define Hh 512
#define NINq 256
#define Pp 471
#define EPSN 1e-8f

__device__ __forceinline__ float sigm(float x){ return 1.0f/(1.0f+expf(-x)); }

// ---------------- prep: zero T1/T2, build xcat, init gates with bias ----------------
// grid-stride over 262144 + 32768 + 65536 = 360448 elements
__global__ void k_prep(const float* __restrict__ X, const float* __restrict__ pr,
                       const float* __restrict__ h0, const float* __restrict__ lb,
                       float* __restrict__ T12, float* __restrict__ xcat,
                       float* __restrict__ gates)
{
  int idx = blockIdx.x*blockDim.x + threadIdx.x;
  if (idx < 262144) { T12[idx] = 0.f; return; }
  idx -= 262144;
  if (idx < 32768) {
    int b = idx >> 10, t = idx & 1023;
    float v;
    if (t < 256) v = X[b*NINq + t];
    else if (t < 512) v = pr[b*(Rr*Mm) + t-256];
    else v = h0[b*Hh + t-512];
    xcat[idx] = v;
    return;
  }
  idx -= 32768;
  if (idx < 65536) {
    int b = idx >> 11, c = idx & 2047;
    gates[b*2048 + c] = lb[c];
  }
}

// ---------------- generic split-K atomic GEMM ----------------
__global__ __launch_bounds__(256) void k_gemm(
    const float* __restrict__ A, int lda,
    const float* __restrict__ W1, const float* __restrict__ W2, int ksplit,
    int ldw, int ncols, int ldo, float* __restrict__ out)
{
  __shared__ float lin[32][64];
  int tid = threadIdx.x;
  int col = blockIdx.x*64 + (tid & 63);
  int bg  = tid >> 6;
  int k0  = blockIdx.y*64;
#pragma unroll
  for (int q=0;q<8;q++){
    int idx = tid + 256*q;
    int bb = idx >> 6, kk = idx & 63;
    lin[bb][kk] = A[bb*lda + k0 + kk];
  }
  __syncthreads();
  if (col >= ncols) return;
  const float* Wr = (k0 < ksplit) ? (W1 + (size_t)k0*ldw)
                                  : (W2 + (size_t)(k0 - ksplit)*ldw);
  float acc[8];
#pragma unroll
  for (int i=0;i<8;i++) acc[i]=0.f;
  for (int kk=0; kk<64; ++kk){
    float wv = Wr[(size_t)kk*ldw + col];
#pragma unroll
    for (int bb=0; bb<8; ++bb) acc[bb] += wv * lin[bg*8+bb][kk];
  }
#pragma unroll
  for (int bb=0; bb<8; ++bb)
    atomicAdd(&out[(size_t)(bg*8+bb)*ldo + col], acc[bb]);
}

// ---------------- LSTM epilogue; scatter h/emb; zero reads; init pvec bias ----------------
__global__ void k_lstm_ep(const float* __restrict__ gates, const float* __restrict__ c0,
                          const float* __restrict__ emb, const float* __restrict__ bp,
                          float* __restrict__ hcat, float* __restrict__ ocat,
                          float* __restrict__ pvec)
{
  int idx = blockIdx.x*blockDim.x + threadIdx.x;
  if (idx >= Bb*Hh) return;
  int b = idx >> 9, j = idx & 511;
  const float* g = gates + b*2048;
  float gi = g[j], gf = g[j+512], gg = g[j+1024], go = g[j+1536];
  float c = sigm(gf)*c0[idx] + sigm(gi)*tanhf(gg);
  float h = sigm(go)*tanhf(c);
  float e = emb[idx];
  hcat[b*1024 + j]       = h;
  hcat[b*1024 + 512 + j] = e;
  ocat[b*1280 + j]       = h;
  ocat[b*1280 + 512 + j] = e;
  if (j < 256) ocat[b*1280 + 1024 + j] = 0.f;   // reads section (atomicAdd target)
  if (j < Pp)  pvec[b*512 + j] = bp[j];         // bias init for para GEMM
}

// ---------------- fused LayerNorm + usage/allocation ----------------
__global__ __launch_bounds__(1024) void k_lnalloc(
    const float* __restrict__ ln_g, const float* __restrict__ ln_b,
    const float* __restrict__ rwp, const float* __restrict__ wwp,
    const float* __restrict__ up,
    float* __restrict__ pvec, float* __restrict__ alloc)
{
  __shared__ float red[8];
  __shared__ float fg[4];
  __shared__ unsigned long long sk[1024];
  __shared__ float wsums[16];
  int b = blockIdx.x, tid = threadIdx.x;
  int lane = tid & 63, wv = tid >> 6;
  // ---- LN phase (threads 0..511) ----
  float acc = 0.f, d = 0.f;
  if (tid < 512) {
    acc = (tid < Pp) ? pvec[b*512 + tid] : 0.f;
    float s = acc;
    for (int o=32;o;o>>=1) s += __shfl_xor(s,o,64);
    if (lane==0) red[wv] = s;
  }
  __syncthreads();
  if (tid < 8){ float xx = red[tid]; for (int o=4;o;o>>=1) xx += __shfl_xor(xx,o,64); if (!tid) red[0]=xx; }
  __syncthreads();
  float mu = red[0] / (float)Pp;
  __syncthreads();
  if (tid < 512) {
    d = (tid < Pp) ? (acc - mu) : 0.f;
    float s2 = d*d;
    for (int o=32;o;o>>=1) s2 += __shfl_xor(s2,o,64);
    if (lane==0) red[wv] = s2;
  }
  __syncthreads();
  if (tid < 8){ float xx = red[tid]; for (int o=4;o;o>>=1) xx += __shfl_xor(xx,o,64); if (!tid) red[0]=xx; }
  __syncthreads();
  float var = red[0] / (float)Pp;
  if (tid < Pp) {
    float y = d / sqrtf(var + 1e-5f) * ln_g[tid] + ln_b[tid];
    pvec[b*512 + tid] = y;
    if (tid >= 128 && tid < 132) fg[tid-128] = sigm(y);
  }
  __syncthreads();
  // ---- alloc phase (all 1024 threads) ----
  float psi = 1.f;
#pragma unroll
  for (int r=0;r<4;r++) psi *= 1.f - fg[r]*rwp[b*(Rr*Nn) + r*Nn + tid];
  float u = up[b*Nn+tid], w = wwp[b*Nn+tid];
  float usage = (u + w - u*w)*psi;               // >= 0 always
  unsigned long long key = ((unsigned long long)__float_as_uint(usage) << 32) | (unsigned)tid;
  for (int k=2; k<=1024; k<<=1) {
    for (int j=k>>1; j>0; j>>=1) {
      bool lower = (tid & j) == 0;
      bool asc   = (tid & k) == 0;
      unsigned long long pk;
      if (j >= 64) {
        sk[tid] = key; __syncthreads();
        pk = sk[tid ^ j];
        __syncthreads();
      } else {
        pk = __shfl_xor(key, j, 64);
      }
      key = ((key < pk) == (lower == asc)) ? key : pk;
    }
  }
  float us = __uint_as_float((unsigned)(key >> 32));
  int order = (int)(key & 1023u);
  float v = us;
#pragma unroll
  for (int dd=1; dd<64; dd<<=1) {
    float p = __shfl_up(v, dd, 64);
    if (lane >= dd) v *= p;
  }
  if (lane == 63) wsums[wv] = v;
  __syncthreads();
  if (wv == 0) {
    float t = (lane < 16) ? wsums[lane] : 1.f;
#pragma unroll
    for (int dd=1; dd<16; dd<<=1) {
      float p = __shfl_up(t, dd, 64);
      if (lane >= dd) t *= p;
    }
    if (lane < 16) wsums[lane] = t;
  }
  __syncthreads();
  float prefix = (wv > 0) ? wsums[wv-1] : 1.f;
  alloc[b*Nn + order] = (1.f - us) * (v * prefix);
}

// ---------------- write-key cosine sim vs OLD memory ----------------
__global__ __launch_bounds__(256) void k_simw(
    const float* __restrict__ pvec, const float* __restrict__ mem,
    float* __restrict__ simw)
{
  __shared__ float kdir[64];
  __shared__ float sc[1];
  int b = blockIdx.y, tid = threadIdx.x;
  int wv = tid>>6, lane = tid&63;
  const float* pv = pvec + b*512;
  if (wv == 0) {
    float v = pv[146 + lane];
    float s = v*v;
    for (int o=32;o;o>>=1) s += __shfl_xor(s,o,64);
    kdir[lane] = v / (sqrtf(s) + EPSN);
    if (lane == 0) sc[0] = 1.f + log1pf(expf(pv[210]));
  }
  __syncthreads();
  float beta = sc[0];
  for (int t=0;t<16;++t){
    int n = blockIdx.x*64 + wv*16 + t;
    float v = mem[(b*Nn+n)*Mm + lane];
    float d = v*kdir[lane], s2 = v*v;
    for (int o=32;o;o>>=1){ d += __shfl_xor(d,o,64); s2 += __shfl_xor(s2,o,64); }
    if (lane == 0) simw[b*Nn+n] = beta * d / (sqrtf(s2) + EPSN);
  }
}

// ---------------- softmax(simw) + gates -> ww, plus Sp/Sw scalars ----------------
__global__ __launch_bounds__(1024) void k_ww2(
    const float* __restrict__ pvec, const float* __restrict__ simw,
    const float* __restrict__ alloc, const float* __restrict__ prec,
    const float* __restrict__ rwp, float* __restrict__ wwb, float* __restrict__ spsw)
{
  __shared__ float red[16];
  __shared__ float red8[16][8];
  __shared__ float scal[2];
  int b = blockIdx.x, tid = threadIdx.x;
  int wv = tid >> 6, lane = tid & 63;
  const float* pv = pvec + b*512;
  if (tid == 0) { scal[0] = sigm(pv[132]); scal[1] = sigm(pv[133]); }
  float v = simw[b*Nn + tid];
  float m_ = v;
  for (int o=32;o;o>>=1) m_ = fmaxf(m_, __shfl_xor(m_,o,64));
  if (lane==0) red[wv] = m_;
  __syncthreads();
  if (tid < 16){ float x = red[tid]; for (int o=8;o;o>>=1) x = fmaxf(x,__shfl_xor(x,o,64)); if (!tid) red[0]=x; }
  __syncthreads();
  float gmax = red[0];
  __syncthreads();
  float e = expf(v - gmax);
  float ss = e;
  for (int o=32;o;o>>=1) ss += __shfl_xor(ss,o,64);
  if (lane==0) red[wv] = ss;
  __syncthreads();
  if (tid < 16){ float x = red[tid]; for (int o=8;o;o>>=1) x += __shfl_xor(x,o,64); if (!tid) red[0]=x; }
  __syncthreads();
  float wcn = e / red[0];
  float ag = scal[0], wg = scal[1];
  float an = alloc[b*Nn + tid];
  float wwn = wg * (ag*an + (1.f-ag)*wcn);
  wwb[b*Nn + tid] = wwn;
  float p = prec[b*Nn + tid];
#pragma unroll
  for (int r=0;r<4;r++){
    float a = rwp[b*(Rr*Nn) + r*Nn + tid];
    float x1 = p*a, x2 = wwn*a;
    for (int o=32;o;o>>=1){ x1 += __shfl_xor(x1,o,64); x2 += __shfl_xor(x2,o,64); }
    if (lane==0){ red8[wv][r] = x1; red8[wv][4+r] = x2; }
  }
  __syncthreads();
  if (tid < 8) {
    float s = 0.f;
    for (int w2=0; w2<16; ++w2) s += red8[w2][tid];
    spsw[b*8 + tid] = s;   // [0..3]=Sp, [4..7]=Sw
  }
}

// ---------------- memory update + fused read-key sims ----------------
__global__ __launch_bounds__(256) void k_memupd(
    const float* __restrict__ pvec, const float* __restrict__ mem,
    const float* __restrict__ wwb, float* __restrict__ memn, float* __restrict__ simr)
{
  __shared__ float ev[64], wvv[64];
  __shared__ float kdir[4][64];
  __shared__ float beta[4];
  int b = blockIdx.y, tid = threadIdx.x;
  int wv = tid>>6, lane = tid&63;
  const float* pv = pvec + b*512;
  {
    float kv = pv[211 + wv*64 + lane];
    float s = kv*kv;
    for (int o=32;o;o>>=1) s += __shfl_xor(s,o,64);
    kdir[wv][lane] = kv/(sqrtf(s)+EPSN);
    if (lane==0) beta[wv] = 1.f + log1pf(expf(pv[467+wv]));
  }
  if (tid < 64) { wvv[tid] = pv[tid]; ev[tid] = sigm(pv[64+tid]); }
  __syncthreads();
  for (int t=0;t<16;++t){
    int n = blockIdx.x*64 + wv*16 + t;
    float wwn = wwb[b*Nn + n];
    float v = mem[(b*Nn+n)*Mm + lane];
    float nv = v*(1.f - wwn*ev[lane]) + wwn*wvv[lane];
    memn[(b*Nn+n)*Mm + lane] = nv;
    float s2 = nv*nv;
    float d0 = nv*kdir[0][lane], d1 = nv*kdir[1][lane];
    float d2 = nv*kdir[2][lane], d3 = nv*kdir[3][lane];
    for (int o=32;o;o>>=1){
      s2 += __shfl_xor(s2,o,64);
      d0 += __shfl_xor(d0,o,64); d1 += __shfl_xor(d1,o,64);
      d2 += __shfl_xor(d2,o,64); d3 += __shfl_xor(d3,o,64);
    }
    if (lane==0){
      float inv = 1.f/(sqrtf(s2)+EPSN);
      simr[(b*4+0)*Nn+n] = beta[0]*d0*inv;
      simr[(b*4+1)*Nn+n] = beta[1]*d1*inv;
      simr[(b*4+2)*Nn+n] = beta[2]*d2*inv;
      simr[(b*4+3)*Nn+n] = beta[3]*d3*inv;
    }
  }
}

// ---------------- single-pass link scan: row dots (S1,S2), col dots (T1,T2), diag ----------------
// grid (16 row-stripes, B), block 256. 64x64 LDS tile read once from HBM.
__global__ __launch_bounds__(256) void k_links(
    const float* __restrict__ links, const float* __restrict__ rwp,
    const float* __restrict__ wwb,
    float* __restrict__ S1, float* __restrict__ S2,
    float* __restrict__ T1, float* __restrict__ T2,
    float* __restrict__ diag)
{
  __shared__ float tile[64][68];
  __shared__ float ai[4][64], wai[4][64], aj[4][64], waj[4][64];
  int b = blockIdx.y, stripe = blockIdx.x, i0 = stripe*64;
  int tid = threadIdx.x;
  {
    int r = tid>>6, ii = tid&63;
    float a = rwp[b*(Rr*Nn) + r*Nn + i0+ii];
    ai[r][ii]  = a;
    wai[r][ii] = a * wwb[b*Nn + i0+ii];
  }
  float s1a[4]={0,0,0,0}, s2a[4]={0,0,0,0};
  const float* Lb = links + (size_t)b*Nn*Nn;
  for (int t=0; t<16; ++t) {
    int j0 = t*64;
    __syncthreads();                       // previous readers done
    {
      int r = tid>>6, jj = tid&63;
      float a = rwp[b*(Rr*Nn) + r*Nn + j0+jj];
      aj[r][jj]  = a;
      waj[r][jj] = a * wwb[b*Nn + j0+jj];
    }
#pragma unroll
    for (int q=0;q<4;q++){
      int f = tid + 256*q;                 // float4 index
      int row = f>>4, c4 = f&15;
      float4 v = *reinterpret_cast<const float4*>(&Lb[(size_t)(i0+row)*Nn + j0 + c4*4]);
      *reinterpret_cast<float4*>(&tile[row][c4*4]) = v;
    }
    __syncthreads();
    if (t == stripe && tid < 64) diag[b*Nn + i0 + tid] = tile[tid][tid];
    // phase A: row partials — thread (ii=tid>>2, c=tid&3) covers cols c*16..+15
    {
      int ii = tid>>2, c = tid&3;
      float p1[4]={0,0,0,0}, p2[4]={0,0,0,0};
      for (int k=0;k<16;k++){
        int jj = c*16+k;
        float v = tile[ii][jj];
#pragma unroll
        for (int r=0;r<4;r++){ p1[r] += v*aj[r][jj]; p2[r] += v*waj[r][jj]; }
      }
#pragma unroll
      for (int r=0;r<4;r++){
        p1[r] += __shfl_xor(p1[r],1,64); p1[r] += __shfl_xor(p1[r],2,64);
        p2[r] += __shfl_xor(p2[r],1,64); p2[r] += __shfl_xor(p2[r],2,64);
      }
      if (c==0){
#pragma unroll
        for (int r=0;r<4;r++){ s1a[r] += p1[r]; s2a[r] += p2[r]; }
      }
    }
    // phase B: col partials — thread (jj=tid>>2, q=tid&3) covers rows q*16..+15
    {
      int jj = tid>>2, q = tid&3;
      float p1[4]={0,0,0,0}, p2[4]={0,0,0,0};
      for (int k=0;k<16;k++){
        int ii = q*16+k;
        float v = tile[ii][jj];
#pragma unroll
        for (int r=0;r<4;r++){ p1[r] += v*ai[r][ii]; p2[r] += v*wai[r][ii]; }
      }
#pragma unroll
      for (int r=0;r<4;r++){
        p1[r] += __shfl_xor(p1[r],1,64); p1[r] += __shfl_xor(p1[r],2,64);
        p2[r] += __shfl_xor(p2[r],1,64); p2[r] += __shfl_xor(p2[r],2,64);
      }
      if (q==0){
#pragma unroll
        for (int r=0;r<4;r++){
          atomicAdd(&T1[(b*4+r)*Nn + j0+jj], p1[r]);
          atomicAdd(&T2[(b*4+r)*Nn + j0+jj], p2[r]);
        }
      }
    }
  }
  if ((tid&3)==0){
    int ii = tid>>2;
#pragma unroll
    for (int r=0;r<4;r++){
      S1[(b*4+r)*Nn + i0+ii] = s1a[r];
      S2[(b*4+r)*Nn + i0+ii] = s2a[r];
    }
  }
}

// ---------------- per-(b,r): softmax(simr) + combine -> rw (in place) ----------------
__global__ __launch_bounds__(1024) void k_rsoft(
    const float* __restrict__ pvec, const float* __restrict__ rwp,
    const float* __restrict__ prec, const float* __restrict__ wwb,
    const float* __restrict__ T1, const float* __restrict__ T2,
    const float* __restrict__ S1, const float* __restrict__ S2,
    const float* __restrict__ spsw, const float* __restrict__ diag,
    float* __restrict__ simr)
{
  __shared__ float red[16];
  __shared__ float rm3[3];
  int b = blockIdx.x, r = blockIdx.y, tid = threadIdx.x;
  int wv = tid>>6, lane = tid&63;
  const float* pv = pvec + b*512;
  if (tid == 0) {
    float x0 = pv[134+r*3], x1 = pv[134+r*3+1], x2 = pv[134+r*3+2];
    float mx = fmaxf(x0, fmaxf(x1,x2));
    float e0 = expf(x0-mx), e1 = expf(x1-mx), e2 = expf(x2-mx);
    float s = e0+e1+e2;
    rm3[0]=e0/s; rm3[1]=e1/s; rm3[2]=e2/s;
  }
  float v = simr[(b*4+r)*Nn + tid];
  float m_ = v;
  for (int o=32;o;o>>=1) m_ = fmaxf(m_, __shfl_xor(m_,o,64));
  if (lane==0) red[wv]=m_;
  __syncthreads();
  if (tid<16){ float x=red[tid]; for(int o=8;o;o>>=1) x=fmaxf(x,__shfl_xor(x,o,64)); if(!tid) red[0]=x; }
  __syncthreads();
  float gmax = red[0];
  __syncthreads();
  float e = expf(v-gmax);
  float s = e;
  for (int o=32;o;o>>=1) s += __shfl_xor(s,o,64);
  if (lane==0) red[wv]=s;
  __syncthreads();
  if (tid<16){ float x=red[tid]; for(int o=8;o;o>>=1) x+=__shfl_xor(x,o,64); if(!tid) red[0]=x; }
  __syncthreads();
  float rc = e/red[0];
  float w_n = wwb[b*Nn + tid];
  float p_n = prec[b*Nn + tid];
  float a = rwp[b*(Rr*Nn)+r*Nn+tid];
  float Lii = diag[b*Nn + tid];
  float s1v = S1[(b*4+r)*Nn+tid], s2v = S2[(b*4+r)*Nn+tid];
  float t1v = T1[(b*4+r)*Nn+tid], t2v = T2[(b*4+r)*Nn+tid];
  float Spr = spsw[b*8+r], Swr = spsw[b*8+4+r];
  float fwd = (1.f-w_n)*(s1v - Lii*a) - (s2v - Lii*w_n*a) + w_n*(Spr - p_n*a);
  float bwd = (1.f-w_n)*(t1v - Lii*a) - (t2v - w_n*Lii*a) + p_n*(Swr - w_n*a);
  simr[(b*4+r)*Nn + tid] = rm3[1]*rc + rm3[0]*bwd + rm3[2]*fwd;   // rw
}

// ---------------- reads = rw @ memn (atomic n-split); also init out bias ----------------
__global__ __launch_bounds__(256) void k_rgemv(
    const float* __restrict__ simr, const float* __restrict__ memn,
    const float* __restrict__ bo, float* __restrict__ ocat, float* __restrict__ out)
{
  int b = blockIdx.y, ch = blockIdx.x, tid = threadIdx.x;
  if (ch == 0) out[b*256 + tid] = bo[tid];
  int r = tid>>6, m = tid&63;
  float acc = 0.f;
#pragma unroll 8
  for (int t=0;t<128;++t){
    int n = ch*128 + t;
    acc += simr[(b*4+r)*Nn + n] * memn[(b*Nn+n)*Mm + m];
  }
  atomicAdd(&ocat[b*1280 + 1024 + r*64 + m], acc);
}

extern "C" void kernel_launch(void* const* d_in, const int* in_sizes, int n_in,
                              void* d_out, int out_size, void* d_ws, size_t ws_size,
                              hipStream_t stream)
{
  (void)in_sizes; (void)n_in; (void)out_size; (void)ws_size;
  const float* X    = (const float*)d_in[0];
  const float* emb  = (const float*)d_in[1];
  const float* mem  = (const float*)d_in[2];
  const float* prvr = (const float*)d_in[3];
  const float* h0   = (const float*)d_in[4];
  const float* c0   = (const float*)d_in[5];
  const float* rwp  = (const float*)d_in[6];
  const float* wwp  = (const float*)d_in[7];
  const float* up   = (const float*)d_in[8];
  const float* prec = (const float*)d_in[9];
  const float* links= (const float*)d_in[10];
  const float* Wx   = (const float*)d_in[11];
  const float* Wh   = (const float*)d_in[12];
  const float* lb   = (const float*)d_in[13];
  const float* Wp   = (const float*)d_in[14];
  const float* bp   = (const float*)d_in[15];
  const float* lng  = (const float*)d_in[16];
  const float* lnb  = (const float*)d_in[17];
  const float* Wo   = (const float*)d_in[18];
  const float* bo   = (const float*)d_in[19];
  float* out = (float*)d_out;
  float* ws  = (float*)d_ws;

  float* memn  = ws;                       // 2097152
  float* T1    = memn  + 2097152;          // 131072
  float* T2    = T1    + 131072;           // 131072
  float* S1    = T2    + 131072;           // 131072
  float* S2    = S1    + 131072;           // 131072
  float* pvec  = S2    + 131072;           // 16384 (stride 512, 471 used)
  float* alloc = pvec  + 16384;            // 32768
  float* wwb   = alloc + 32768;            // 32768
  float* ocat  = wwb   + 32768;            // 40960  [h|emb|reads]
  float* spsw  = ocat  + 40960;            // 256
  float* simr  = spsw  + 256;              // 131072 (then rw in place)
  float* diag  = simr  + 131072;           // 32768
  float* xcat  = diag  + 32768;            // 32768  [X|prev_read|h0]
  float* hcat  = xcat  + 32768;            // 32768  [h|emb]
  float* gates = hcat  + 32768;            // 65536

  k_prep   <<<dim3(1408),   dim3(256),  0, stream>>>(X, prvr, h0, lb, T1, xcat, gates);
  k_gemm   <<<dim3(32,16),  dim3(256),  0, stream>>>(xcat, 1024, Wx, Wh, 512, 2048, 2048, 2048, gates);
  k_lstm_ep<<<dim3(64),     dim3(256),  0, stream>>>(gates, c0, emb, bp, hcat, ocat, pvec);
  k_gemm   <<<dim3(8,16),   dim3(256),  0, stream>>>(hcat, 1024, Wp, Wp, 1<<30, 471, 471, 512, pvec);
  k_lnalloc<<<dim3(32),     dim3(1024), 0, stream>>>(lng, lnb, rwp, wwp, up, pvec, alloc);
  k_simw   <<<dim3(16,32),  dim3(256),  0, stream>>>(pvec, mem, simr);   // simr scratch; overwritten later? no: simw uses first 32768 of simr? -- use dedicated region below
  k_ww2    <<<dim3(32),     dim3(1024), 0, stream>>>(pvec, simr, alloc, prec, rwp, wwb, spsw);
  k_memupd <<<dim3(16,32),  dim3(256),  0, stream>>>(pvec, mem, wwb, memn, simr);
  k_links  <<<dim3(16,32),  dim3(256),  0, stream>>>(links, rwp, wwb, S1, S2, T1, T2, diag);
  k_rsoft  <<<dim3(32,4),   dim3(1024), 0, stream>>>(pvec, rwp, prec, wwb, T1, T2, S1, S2, spsw, diag, simr);
  k_rgemv  <<<dim3(8,32),   dim3(256),  0, stream>>>(simr, memn, bo, ocat, out);
  k_gemm   <<<dim3(4,20),   dim3(256),  0, stream>>>(ocat, 1280, Wo, Wo, 1<<30, 256, 256, 256, out);
}